// Round 3
// baseline (943.778 us; speedup 1.0000x reference)
//
#include <hip/hip_runtime.h>
#include <math.h>

#define PLANE 16384   // 128*128
#define NPLANES 512   // B(128) * C(4)

// ---------------- in-register 2D FWHT-128x128 across a 256-thread block ----------------
// Thread (W = tid>>6, L = tid&63) holds v[g*4+c] = plane[h][w],
//   h = W*32 + (L>>5)*16 + g   (g in [0,16))
//   w = (L&31)*4 + c           (c in [0,4))
// Bit split:  w bits 0-1 -> reg bits 0-1 ; w bits 2-6 -> L bits 0-4
//             h bits 0-3 -> reg bits 2-5 ; h bit 4 -> L bit 5 ; h bits 5-6 -> W
__device__ __forceinline__ void fwht2d_reg(float* __restrict__ v, float* __restrict__ xch,
                                           int W, int L) {
    // w bits 0-1: in-register
#pragma unroll
    for (int m = 1; m <= 2; m <<= 1) {
#pragma unroll
        for (int r = 0; r < 64; ++r) {
            if (!(r & m)) {
                int s = r | m;
                float a = v[r], b = v[s];
                v[r] = a + b; v[s] = a - b;
            }
        }
    }
    // w bits 2-6 and h bit 4: cross-lane shuffle stages
#pragma unroll
    for (int m = 1; m <= 32; m <<= 1) {
        float sg = (L & m) ? -1.f : 1.f;
#pragma unroll
        for (int r = 0; r < 64; ++r) {
            float p = __shfl_xor(v[r], m);
            v[r] = fmaf(sg, v[r], p);
        }
    }
    // h bits 0-3: in-register
#pragma unroll
    for (int m = 4; m <= 32; m <<= 1) {
#pragma unroll
        for (int r = 0; r < 64; ++r) {
            if (!(r & m)) {
                int s = r | m;
                float a = v[r], b = v[s];
                v[r] = a + b; v[s] = a - b;
            }
        }
    }
    // h bits 5-6 (wave index): LDS exchange, 2 stages x 2 reg-chunks, conflict-free layout
#pragma unroll
    for (int mw = 1; mw <= 2; mw <<= 1) {
        int Wp = W ^ mw;
        float sg = (W & mw) ? -1.f : 1.f;
#pragma unroll
        for (int half = 0; half < 2; ++half) {
            __syncthreads();
#pragma unroll
            for (int j = 0; j < 32; ++j)
                xch[(j * 4 + W) * 64 + L] = v[half * 32 + j];
            __syncthreads();
#pragma unroll
            for (int j = 0; j < 32; ++j) {
                float p = xch[(j * 4 + Wp) * 64 + L];
                v[half * 32 + j] = fmaf(sg, v[half * 32 + j], p);
            }
        }
    }
}

template <bool STORET, bool ADD>
__global__ __launch_bounds__(256) void fwht_kernel_t(
    const float* __restrict__ in, const float* __restrict__ vmat,
    const float* __restrict__ tmat, const float* __restrict__ addbuf,
    float* __restrict__ outThresh, float* __restrict__ outInv,
    float* __restrict__ klbins)
{
    __shared__ float xch[32 * 256]; // 32 KiB
    const int tid = threadIdx.x;
    const int W = tid >> 6, L = tid & 63;
    const int plane = blockIdx.x;
    const int hbase = W * 32 + ((L >> 5) << 4);
    const int wbase = (L & 31) << 2;
    const float* src = in + (size_t)plane * PLANE;

    float v[64];
#pragma unroll
    for (int g = 0; g < 16; ++g) {
        float4 t = *(const float4*)&src[(hbase + g) * 128 + wbase];
        v[4 * g] = t.x; v[4 * g + 1] = t.y; v[4 * g + 2] = t.z; v[4 * g + 3] = t.w;
    }

    fwht2d_reg(v, xch, W, L);

    // pointwise: *vmat, hard-threshold, KL accumulate, optional store / add
    float ls0 = 0.f, ls1 = 0.f, ls2 = 0.f, ls3 = 0.f;
#pragma unroll
    for (int g = 0; g < 16; ++g) {
        int rowoff = (hbase + g) * 128 + wbase;
        float4 vm = *(const float4*)&vmat[rowoff];
        float4 tm = *(const float4*)&tmat[rowoff];
        float y0 = v[4 * g]     * vm.x;
        float y1 = v[4 * g + 1] * vm.y;
        float y2 = v[4 * g + 2] * vm.z;
        float y3 = v[4 * g + 3] * vm.w;
        y0 = (fabsf(y0) > fabsf(tm.x)) ? y0 : 0.f;
        y1 = (fabsf(y1) > fabsf(tm.y)) ? y1 : 0.f;
        y2 = (fabsf(y2) > fabsf(tm.z)) ? y2 : 0.f;
        y3 = (fabsf(y3) > fabsf(tm.w)) ? y3 : 0.f;
        ls0 += 1.f / (1.f + __expf(-fabsf(y0)));
        ls1 += 1.f / (1.f + __expf(-fabsf(y1)));
        ls2 += 1.f / (1.f + __expf(-fabsf(y2)));
        ls3 += 1.f / (1.f + __expf(-fabsf(y3)));
        if (STORET) {
            float4 o; o.x = y0; o.y = y1; o.z = y2; o.w = y3;
            *(float4*)&outThresh[(size_t)plane * PLANE + rowoff] = o;
        }
        if (ADD) {
            float4 ad = *(const float4*)&addbuf[(size_t)plane * PLANE + rowoff];
            y0 += ad.x; y1 += ad.y; y2 += ad.z; y3 += ad.w;
        }
        v[4 * g] = y0; v[4 * g + 1] = y1; v[4 * g + 2] = y2; v[4 * g + 3] = y3;
    }
    // KL bins: bin = w%64 = (L&15)*4 + c. Reduce lanes sharing (L&15), then atomics.
#pragma unroll
    for (int m = 16; m <= 32; m <<= 1) {
        ls0 += __shfl_xor(ls0, m);
        ls1 += __shfl_xor(ls1, m);
        ls2 += __shfl_xor(ls2, m);
        ls3 += __shfl_xor(ls3, m);
    }
    if (L < 16) {
        atomicAdd(&klbins[4 * L + 0], ls0);
        atomicAdd(&klbins[4 * L + 1], ls1);
        atomicAdd(&klbins[4 * L + 2], ls2);
        atomicAdd(&klbins[4 * L + 3], ls3);
    }

    fwht2d_reg(v, xch, W, L);

    // scale 1/16384, crop to 122x122 (zero pad), store
    float* dst = outInv + (size_t)plane * PLANE;
    const float s = 1.f / 16384.f;
#pragma unroll
    for (int g = 0; g < 16; ++g) {
        int h = hbase + g;
        bool rv = h < 122;
        float4 o;
        o.x = (rv && wbase + 0 < 122) ? v[4 * g]     * s : 0.f;
        o.y = (rv && wbase + 1 < 122) ? v[4 * g + 1] * s : 0.f;
        o.z = (rv && wbase + 2 < 122) ? v[4 * g + 2] * s : 0.f;
        o.w = (rv && wbase + 3 < 122) ? v[4 * g + 3] * s : 0.f;
        *(float4*)&dst[h * 128 + wbase] = o;
    }
}

// ---------------- weight prep: canonicalize w3 (transposed 7x7) and w4 (convT 16x16 s2) ----------------
__global__ void prep_weights(const float* __restrict__ w3, const float* __restrict__ w4,
                             float* __restrict__ w3c, float* __restrict__ w4p)
{
    int tid = blockIdx.x * 256 + threadIdx.x;
    if (tid < 784) {
        int oc = tid / 196;
        int rem = tid - oc * 196;
        int ic = rem / 49;
        int k = rem - ic * 49;
        int kh = k / 7, kw = k - kh * 7;
        w3c[(oc * 4 + ic) * 49 + k] = w3[(ic * 4 + oc) * 49 + (6 - kh) * 7 + (6 - kw)];
    }
    if (tid < 1024) {
        // layout [ic:2][pa:1][pb:1][t:3][u:3]
        int u = tid & 7, t = (tid >> 3) & 7, pb = (tid >> 6) & 1, pa = (tid >> 7) & 1, ic = tid >> 8;
        int kh = 2 * t + (pa ? 0 : 1);
        int kw = 2 * u + (pb ? 0 : 1);
        w4p[tid] = w4[ic * 256 + kh * 16 + kw];
    }
}

// ---------------- conv1: 1->4, k16, s2, p1 : x[B,1,256,256] -> [B,4,128,128] padded ----------------
__global__ __launch_bounds__(256) void conv1_kernel(
    const float* __restrict__ x, const float* __restrict__ w1,
    const float* __restrict__ b1, float* __restrict__ out)
{
    __shared__ float tile[78][80];
    int tx = blockIdx.x, ty = blockIdx.y, b = blockIdx.z;
    int tid = threadIdx.x;
    const float* xp = x + (size_t)b * 65536;
    int r0g = ty * 64 - 1, c0g = tx * 64 - 1;
    for (int i = tid; i < 78 * 78; i += 256) {
        int rr = i / 78, cc = i - rr * 78;
        int gi = r0g + rr, gj = c0g + cc;
        tile[rr][cc] = (gi >= 0 && gi < 256 && gj >= 0 && gj < 256) ? xp[gi * 256 + gj] : 0.f;
    }
    __syncthreads();
    int cg = tid & 7, r = tid >> 3;
    int B = cg * 4;
    float acc[4][4];
#pragma unroll
    for (int oc = 0; oc < 4; ++oc)
#pragma unroll
        for (int c = 0; c < 4; ++c) acc[oc][c] = 0.f;
#pragma unroll 1
    for (int kh = 0; kh < 16; ++kh) {
        float win[24];
        const float* trow = &tile[2 * r + kh][2 * B];
#pragma unroll
        for (int k = 0; k < 6; ++k)
            *(float4*)&win[4 * k] = *(const float4*)&trow[4 * k];
#pragma unroll
        for (int oc = 0; oc < 4; ++oc) {
            const float* wr = w1 + oc * 256 + kh * 16;
#pragma unroll
            for (int kw = 0; kw < 16; ++kw) {
                float wv = wr[kw];
#pragma unroll
                for (int c = 0; c < 4; ++c)
                    acc[oc][c] = fmaf(win[2 * c + kw], wv, acc[oc][c]);
            }
        }
    }
    int oh = ty * 32 + r;
    int owb = tx * 32 + B;
    bool rowv = oh < 122;
#pragma unroll
    for (int oc = 0; oc < 4; ++oc) {
        float bv = b1[oc];
        float4 res;
        res.x = (rowv && owb + 0 < 122) ? acc[oc][0] + bv : 0.f;
        res.y = (rowv && owb + 1 < 122) ? acc[oc][1] + bv : 0.f;
        res.z = (rowv && owb + 2 < 122) ? acc[oc][2] + bv : 0.f;
        res.w = (rowv && owb + 3 < 122) ? acc[oc][3] + bv : 0.f;
        *(float4*)&out[(((size_t)b * 4 + oc) << 14) + (oh << 7) + owb] = res;
    }
}

// ---------------- 7x7 conv, 4->4, pad 3, canonical weights [oc][ic][kh][kw], optional skip ----------------
__global__ __launch_bounds__(256) void conv7_kernel(
    const float* __restrict__ in, const float* __restrict__ w,
    const float* __restrict__ bias, const float* __restrict__ skip,
    float* __restrict__ out)
{
    __shared__ float tile[4][38][40];
    int tx = blockIdx.x, ty = blockIdx.y, b = blockIdx.z;
    int tid = threadIdx.x;
    int r0g = ty * 32 - 3, c0g = tx * 32 - 3;
    for (int i = tid; i < 4 * 38 * 38; i += 256) {
        int ic = i / 1444;
        int rem = i - ic * 1444;
        int rr = rem / 38, cc = rem - rr * 38;
        int gi = r0g + rr, gj = c0g + cc;
        float v = 0.f;
        if (gi >= 0 && gi < 128 && gj >= 0 && gj < 128)
            v = in[(((size_t)b * 4 + ic) << 14) + (gi << 7) + gj];
        tile[ic][rr][cc] = v;
    }
    __syncthreads();
    int cg = tid & 7, r = tid >> 3;
    int B = cg * 4;
    float acc[4][4];
#pragma unroll
    for (int oc = 0; oc < 4; ++oc)
#pragma unroll
        for (int c = 0; c < 4; ++c) acc[oc][c] = 0.f;
#pragma unroll 1
    for (int ic = 0; ic < 4; ++ic) {
#pragma unroll 1
        for (int kh = 0; kh < 7; ++kh) {
            float win[12];
            const float* trow = &tile[ic][r + kh][B];
#pragma unroll
            for (int k = 0; k < 3; ++k)
                *(float4*)&win[4 * k] = *(const float4*)&trow[4 * k];
#pragma unroll
            for (int oc = 0; oc < 4; ++oc) {
                const float* wr = w + (oc * 4 + ic) * 49 + kh * 7;
#pragma unroll
                for (int kw = 0; kw < 7; ++kw) {
                    float wv = wr[kw];
#pragma unroll
                    for (int c = 0; c < 4; ++c)
                        acc[oc][c] = fmaf(win[c + kw], wv, acc[oc][c]);
                }
            }
        }
    }
    int oh = ty * 32 + r;
    int owb = tx * 32 + B;
    bool rowv = oh < 122;
#pragma unroll
    for (int oc = 0; oc < 4; ++oc) {
        size_t o = (((size_t)b * 4 + oc) << 14) + (oh << 7) + owb;
        float4 sv = make_float4(0.f, 0.f, 0.f, 0.f);
        if (skip) sv = *(const float4*)&skip[o];
        float bv = bias[oc];
        float4 res;
        res.x = (rowv && owb + 0 < 122) ? acc[oc][0] + bv + sv.x : 0.f;
        res.y = (rowv && owb + 1 < 122) ? acc[oc][1] + bv + sv.y : 0.f;
        res.z = (rowv && owb + 2 < 122) ? acc[oc][2] + bv + sv.z : 0.f;
        res.w = (rowv && owb + 3 < 122) ? acc[oc][3] + bv + sv.w : 0.f;
        *(float4*)&out[o] = res;
    }
}

// ---------------- convT4: 4->1, k16, s2, p1, parity-decomposed; then * x ----------------
#define CT_HALF(T, ROW, PA)                                                    \
    _Pragma("unroll")                                                          \
    for (int pb = 0; pb < 2; ++pb) {                                           \
        const float* w8 = wp + (((ic * 2 + (PA)) * 2 + pb) * 8 + (T)) * 8;     \
        _Pragma("unroll")                                                      \
        for (int u = 0; u < 8; ++u) {                                          \
            float wv = w8[u];                                                  \
            _Pragma("unroll")                                                  \
            for (int c = 0; c < 4; ++c)                                        \
                acc[PA][pb][c] = fmaf(ROW[8 + c + pb - u], wv, acc[PA][pb][c]);\
        }                                                                      \
    }

__global__ __launch_bounds__(256) void convt4_kernel(
    const float* __restrict__ in, const float* __restrict__ wp,
    const float* __restrict__ bias, const float* __restrict__ xin,
    float* __restrict__ out)
{
    __shared__ float tile[4][40][44];
    int tx = blockIdx.x, ty = blockIdx.y, b = blockIdx.z;
    int tid = threadIdx.x;
    int A0 = ty * 32, B0 = tx * 32;
    int r0g = A0 - 7, c0g = B0 - 8;
    for (int i = tid; i < 4 * 40 * 44; i += 256) {
        int ic = i / 1760;
        int rem = i - ic * 1760;
        int rr = rem / 44, cc = rem - rr * 44;
        int gi = r0g + rr, gj = c0g + cc;
        float v = 0.f;
        if (gi >= 0 && gi < 128 && gj >= 0 && gj < 128)
            v = in[(((size_t)b * 4 + ic) << 14) + (gi << 7) + gj];
        tile[ic][rr][cc] = v;
    }
    __syncthreads();
    int cg = tid & 7, ra = tid >> 3;
    float acc[2][2][4];
#pragma unroll
    for (int pa = 0; pa < 2; ++pa)
#pragma unroll
        for (int pb = 0; pb < 2; ++pb)
#pragma unroll
            for (int c = 0; c < 4; ++c) acc[pa][pb][c] = 0.f;
#pragma unroll 1
    for (int ic = 0; ic < 4; ++ic) {
        float bufA[16], bufB[16];
#pragma unroll
        for (int k = 0; k < 4; ++k)
            *(float4*)&bufB[4 * k] = *(const float4*)&tile[ic][ra + 8][4 * cg + 4 * k];
#pragma unroll 1
        for (int t2 = 0; t2 < 8; t2 += 2) {
#pragma unroll
            for (int k = 0; k < 4; ++k)
                *(float4*)&bufA[4 * k] = *(const float4*)&tile[ic][ra + 7 - t2][4 * cg + 4 * k];
            CT_HALF(t2, bufA, 0)
            CT_HALF(t2, bufB, 1)
#pragma unroll
            for (int k = 0; k < 4; ++k)
                *(float4*)&bufB[4 * k] = *(const float4*)&tile[ic][ra + 6 - t2][4 * cg + 4 * k];
            CT_HALF(t2 + 1, bufB, 0)
            CT_HALF(t2 + 1, bufA, 1)
        }
    }
    int oh0 = 2 * (A0 + ra);
    int owb = 2 * (B0 + 4 * cg);
    float bv = bias[0];
#pragma unroll
    for (int pa = 0; pa < 2; ++pa) {
        size_t o = (size_t)b * 65536 + (size_t)(oh0 + pa) * 256 + owb;
        float4 x0 = *(const float4*)&xin[o];
        float4 x1 = *(const float4*)&xin[o + 4];
        float4 r0, r1;
        r0.x = (acc[pa][0][0] + bv) * x0.x;
        r0.y = (acc[pa][1][0] + bv) * x0.y;
        r0.z = (acc[pa][0][1] + bv) * x0.z;
        r0.w = (acc[pa][1][1] + bv) * x0.w;
        r1.x = (acc[pa][0][2] + bv) * x1.x;
        r1.y = (acc[pa][1][2] + bv) * x1.y;
        r1.z = (acc[pa][0][3] + bv) * x1.z;
        r1.w = (acc[pa][1][3] + bv) * x1.w;
        *(float4*)&out[o] = r0;
        *(float4*)&out[o + 4] = r1;
    }
}

// ---------------- TV loss ----------------
__global__ __launch_bounds__(256) void tv_kernel(
    const float* __restrict__ out, float* __restrict__ acc)
{
    __shared__ float red[256];
    int tid = threadIdx.x;
    float local = 0.f;
    const int total = 128 * 65536;
    for (int idx = blockIdx.x * 256 + tid; idx < total; idx += gridDim.x * 256) {
        float v = out[idx];
        int hw = idx & 65535;
        if (hw < 65280) local += fabsf(out[idx + 256] - v);
        if ((idx & 255) != 255) local += fabsf(out[idx + 1] - v);
    }
    red[tid] = local;
    __syncthreads();
    for (int s = 128; s > 0; s >>= 1) {
        if (tid < s) red[tid] += red[tid + s];
        __syncthreads();
    }
    if (tid == 0) atomicAdd(acc, red[0]);
}

// ---------------- init / finalize ----------------
__global__ void init_kernel(float* accum) {
    accum[threadIdx.x] = 0.f;
}

__global__ void finalize_kernel(const float* __restrict__ accum, float* __restrict__ lossout) {
    int t = threadIdx.x; // 64 threads = 1 wave
    float p = 1.f / (1.f + __expf(-0.001f));
    float term = 0.f;
    for (int s = 0; s < 3; ++s) {
        float qm = accum[s * 64 + t] * (1.f / 131072.f);
        term += p * logf(p / qm) + (1.f - p) * logf((1.f - p) / (1.f - qm));
    }
    for (int off = 32; off > 0; off >>= 1) term += __shfl_down(term, off);
    if (t == 0) {
        float tv = accum[192];
        lossout[0] = 0.05f * tv / 8388608.f + 0.1f * term;
    }
}

extern "C" void kernel_launch(void* const* d_in, const int* in_sizes, int n_in,
                              void* d_out, int out_size, void* d_ws, size_t ws_size,
                              hipStream_t stream) {
    (void)in_sizes; (void)n_in; (void)out_size; (void)ws_size;
    const float* x  = (const float*)d_in[0];
    const float* v1 = (const float*)d_in[2];
    const float* T1 = (const float*)d_in[3];
    const float* v2 = (const float*)d_in[4];
    const float* T2 = (const float*)d_in[5];
    const float* v3 = (const float*)d_in[6];
    const float* T3 = (const float*)d_in[7];
    const float* w1 = (const float*)d_in[8];
    const float* b1 = (const float*)d_in[9];
    const float* w2 = (const float*)d_in[10];
    const float* b2 = (const float*)d_in[11];
    const float* w3 = (const float*)d_in[12];
    const float* b3 = (const float*)d_in[13];
    const float* w4 = (const float*)d_in[14];
    const float* b4 = (const float*)d_in[15];
    float* out = (float*)d_out;

    float* W0 = (float*)d_ws;
    float* W1 = W0 + (size_t)NPLANES * PLANE;
    float* W2 = W1 + (size_t)NPLANES * PLANE;
    float* accum = W2 + (size_t)NPLANES * PLANE; // [0:64) kl1 [64:128) kl2 [128:192) kl3 [192] tv
    float* w3c = accum + 256;   // 784 floats
    float* w4p = w3c + 784;     // 1024 floats
    float* x10buf = out;        // reuse d_out region as x10 scratch

    init_kernel<<<1, 256, 0, stream>>>(accum);
    prep_weights<<<4, 256, 0, stream>>>(w3, w4, w3c, w4p);
    // x1 (padded) -> W0
    conv1_kernel<<<dim3(4, 4, 128), 256, 0, stream>>>(x, w1, b1, W0);
    // x6 -> W1, x9 -> W2, KL1
    fwht_kernel_t<true, false><<<NPLANES, 256, 0, stream>>>(W0, v1, T1, nullptr, W1, W2, accum + 0);
    // x10 -> d_out scratch
    conv7_kernel<<<dim3(4, 4, 128), 256, 0, stream>>>(W2, w2, b2, nullptr, x10buf);
    // x15 (not stored), KL2, x18 -> W0
    fwht_kernel_t<false, false><<<NPLANES, 256, 0, stream>>>(x10buf, v2, T2, nullptr, nullptr, W0, accum + 64);
    // x19 = convT3(x18) + x10 -> W2
    conv7_kernel<<<dim3(4, 4, 128), 256, 0, stream>>>(W0, w3c, b3, x10buf, W2);
    // x24 (not stored), KL3, +x6, x27 -> W0
    fwht_kernel_t<false, true><<<NPLANES, 256, 0, stream>>>(W2, v3, T3, W1, nullptr, W0, accum + 128);
    // out = convT4(x27) * x
    convt4_kernel<<<dim3(4, 4, 128), 256, 0, stream>>>(W0, w4p, b4, x, out);
    // TV on out
    tv_kernel<<<2048, 256, 0, stream>>>(out, accum + 192);
    // loss scalar
    finalize_kernel<<<1, 64, 0, stream>>>(accum, out + 8388608);
}

// Round 4
// 511.356 us; speedup vs baseline: 1.8456x; 1.8456x over previous
//
#include <hip/hip_runtime.h>
#include <math.h>

#define PLANE 16384   // 128*128
#define NPLANES 512   // B(128) * C(4)

// ---------------- in-register 2D FWHT-128x128 across a 256-thread block ----------------
// Thread (W = tid>>6, L = tid&63) holds v[g*4+c] = plane[h][w],
//   h = W*32 + (L>>5)*16 + g   (g in [0,16))
//   w = (L&31)*4 + c           (c in [0,4))
__device__ __forceinline__ void fwht2d_reg(float* __restrict__ v, float* __restrict__ xch,
                                           int W, int L) {
    // w bits 0-1: in-register
#pragma unroll
    for (int m = 1; m <= 2; m <<= 1) {
#pragma unroll
        for (int r = 0; r < 64; ++r) {
            if (!(r & m)) {
                int s = r | m;
                float a = v[r], b = v[s];
                v[r] = a + b; v[s] = a - b;
            }
        }
    }
    // w bits 2-6 and h bit 4: cross-lane shuffle stages
#pragma unroll
    for (int m = 1; m <= 32; m <<= 1) {
        float sg = (L & m) ? -1.f : 1.f;
#pragma unroll
        for (int r = 0; r < 64; ++r) {
            float p = __shfl_xor(v[r], m);
            v[r] = fmaf(sg, v[r], p);
        }
    }
    // h bits 0-3: in-register
#pragma unroll
    for (int m = 4; m <= 32; m <<= 1) {
#pragma unroll
        for (int r = 0; r < 64; ++r) {
            if (!(r & m)) {
                int s = r | m;
                float a = v[r], b = v[s];
                v[r] = a + b; v[s] = a - b;
            }
        }
    }
    // h bits 5-6 (wave index): LDS exchange, 2 stages x 2 reg-chunks, conflict-free layout
#pragma unroll
    for (int mw = 1; mw <= 2; mw <<= 1) {
        int Wp = W ^ mw;
        float sg = (W & mw) ? -1.f : 1.f;
#pragma unroll
        for (int half = 0; half < 2; ++half) {
            __syncthreads();
#pragma unroll
            for (int j = 0; j < 32; ++j)
                xch[(j * 4 + W) * 64 + L] = v[half * 32 + j];
            __syncthreads();
#pragma unroll
            for (int j = 0; j < 32; ++j) {
                float p = xch[(j * 4 + Wp) * 64 + L];
                v[half * 32 + j] = fmaf(sg, v[half * 32 + j], p);
            }
        }
    }
}

template <bool STORET, bool ADD>
__global__ __launch_bounds__(256) void fwht_kernel_t(
    const float* __restrict__ in, const float* __restrict__ vmat,
    const float* __restrict__ tmat, const float* __restrict__ addbuf,
    float* __restrict__ outThresh, float* __restrict__ outInv,
    float* __restrict__ klpart)   // per-wave partial rows [NPLANES*4][64]
{
    __shared__ float xch[32 * 256]; // 32 KiB
    const int tid = threadIdx.x;
    const int W = tid >> 6, L = tid & 63;
    const int plane = blockIdx.x;
    const int hbase = W * 32 + ((L >> 5) << 4);
    const int wbase = (L & 31) << 2;
    const float* src = in + (size_t)plane * PLANE;

    float v[64];
#pragma unroll
    for (int g = 0; g < 16; ++g) {
        float4 t = *(const float4*)&src[(hbase + g) * 128 + wbase];
        v[4 * g] = t.x; v[4 * g + 1] = t.y; v[4 * g + 2] = t.z; v[4 * g + 3] = t.w;
    }

    fwht2d_reg(v, xch, W, L);

    // pointwise: *vmat, hard-threshold, KL accumulate, optional store / add
    float ls0 = 0.f, ls1 = 0.f, ls2 = 0.f, ls3 = 0.f;
#pragma unroll
    for (int g = 0; g < 16; ++g) {
        int rowoff = (hbase + g) * 128 + wbase;
        float4 vm = *(const float4*)&vmat[rowoff];
        float4 tm = *(const float4*)&tmat[rowoff];
        float y0 = v[4 * g]     * vm.x;
        float y1 = v[4 * g + 1] * vm.y;
        float y2 = v[4 * g + 2] * vm.z;
        float y3 = v[4 * g + 3] * vm.w;
        y0 = (fabsf(y0) > fabsf(tm.x)) ? y0 : 0.f;
        y1 = (fabsf(y1) > fabsf(tm.y)) ? y1 : 0.f;
        y2 = (fabsf(y2) > fabsf(tm.z)) ? y2 : 0.f;
        y3 = (fabsf(y3) > fabsf(tm.w)) ? y3 : 0.f;
        ls0 += 1.f / (1.f + __expf(-fabsf(y0)));
        ls1 += 1.f / (1.f + __expf(-fabsf(y1)));
        ls2 += 1.f / (1.f + __expf(-fabsf(y2)));
        ls3 += 1.f / (1.f + __expf(-fabsf(y3)));
        if (STORET) {
            float4 o; o.x = y0; o.y = y1; o.z = y2; o.w = y3;
            *(float4*)&outThresh[(size_t)plane * PLANE + rowoff] = o;
        }
        if (ADD) {
            float4 ad = *(const float4*)&addbuf[(size_t)plane * PLANE + rowoff];
            y0 += ad.x; y1 += ad.y; y2 += ad.z; y3 += ad.w;
        }
        v[4 * g] = y0; v[4 * g + 1] = y1; v[4 * g + 2] = y2; v[4 * g + 3] = y3;
    }
    // KL bins: bin = w%64 = (L&15)*4 + c. Reduce lanes sharing (L&15), then one
    // coalesced float4 store per wave into a private partial row (NO atomics).
#pragma unroll
    for (int m = 16; m <= 32; m <<= 1) {
        ls0 += __shfl_xor(ls0, m);
        ls1 += __shfl_xor(ls1, m);
        ls2 += __shfl_xor(ls2, m);
        ls3 += __shfl_xor(ls3, m);
    }
    if (L < 16) {
        float4 o; o.x = ls0; o.y = ls1; o.z = ls2; o.w = ls3;
        *(float4*)&klpart[(size_t)(plane * 4 + W) * 64 + 4 * L] = o;
    }

    fwht2d_reg(v, xch, W, L);

    // scale 1/16384, crop to 122x122 (zero pad), store
    float* dst = outInv + (size_t)plane * PLANE;
    const float s = 1.f / 16384.f;
#pragma unroll
    for (int g = 0; g < 16; ++g) {
        int h = hbase + g;
        bool rv = h < 122;
        float4 o;
        o.x = (rv && wbase + 0 < 122) ? v[4 * g]     * s : 0.f;
        o.y = (rv && wbase + 1 < 122) ? v[4 * g + 1] * s : 0.f;
        o.z = (rv && wbase + 2 < 122) ? v[4 * g + 2] * s : 0.f;
        o.w = (rv && wbase + 3 < 122) ? v[4 * g + 3] * s : 0.f;
        *(float4*)&dst[h * 128 + wbase] = o;
    }
}

// ---------------- weight prep: canonicalize w3 (transposed 7x7) and w4 (convT 16x16 s2) ----------------
__global__ void prep_weights(const float* __restrict__ w3, const float* __restrict__ w4,
                             float* __restrict__ w3c, float* __restrict__ w4p)
{
    int tid = blockIdx.x * 256 + threadIdx.x;
    if (tid < 784) {
        int oc = tid / 196;
        int rem = tid - oc * 196;
        int ic = rem / 49;
        int k = rem - ic * 49;
        int kh = k / 7, kw = k - kh * 7;
        w3c[(oc * 4 + ic) * 49 + k] = w3[(ic * 4 + oc) * 49 + (6 - kh) * 7 + (6 - kw)];
    }
    if (tid < 1024) {
        // layout [ic:2][pa:1][pb:1][t:3][u:3]
        int u = tid & 7, t = (tid >> 3) & 7, pb = (tid >> 6) & 1, pa = (tid >> 7) & 1, ic = tid >> 8;
        int kh = 2 * t + (pa ? 0 : 1);
        int kw = 2 * u + (pb ? 0 : 1);
        w4p[tid] = w4[ic * 256 + kh * 16 + kw];
    }
}

// ---------------- conv1: 1->4, k16, s2, p1 : x[B,1,256,256] -> [B,4,128,128] padded ----------------
__global__ __launch_bounds__(256) void conv1_kernel(
    const float* __restrict__ x, const float* __restrict__ w1,
    const float* __restrict__ b1, float* __restrict__ out)
{
    __shared__ float tile[78][80];
    int tx = blockIdx.x, ty = blockIdx.y, b = blockIdx.z;
    int tid = threadIdx.x;
    const float* xp = x + (size_t)b * 65536;
    int r0g = ty * 64 - 1, c0g = tx * 64 - 1;
    for (int i = tid; i < 78 * 78; i += 256) {
        int rr = i / 78, cc = i - rr * 78;
        int gi = r0g + rr, gj = c0g + cc;
        tile[rr][cc] = (gi >= 0 && gi < 256 && gj >= 0 && gj < 256) ? xp[gi * 256 + gj] : 0.f;
    }
    __syncthreads();
    int cg = tid & 7, r = tid >> 3;
    int B = cg * 4;
    float acc[4][4];
#pragma unroll
    for (int oc = 0; oc < 4; ++oc)
#pragma unroll
        for (int c = 0; c < 4; ++c) acc[oc][c] = 0.f;
#pragma unroll 1
    for (int kh = 0; kh < 16; ++kh) {
        float win[24];
        const float* trow = &tile[2 * r + kh][2 * B];
#pragma unroll
        for (int k = 0; k < 6; ++k)
            *(float4*)&win[4 * k] = *(const float4*)&trow[4 * k];
#pragma unroll
        for (int oc = 0; oc < 4; ++oc) {
            const float* wr = w1 + oc * 256 + kh * 16;
#pragma unroll
            for (int kw = 0; kw < 16; ++kw) {
                float wv = wr[kw];
#pragma unroll
                for (int c = 0; c < 4; ++c)
                    acc[oc][c] = fmaf(win[2 * c + kw], wv, acc[oc][c]);
            }
        }
    }
    int oh = ty * 32 + r;
    int owb = tx * 32 + B;
    bool rowv = oh < 122;
#pragma unroll
    for (int oc = 0; oc < 4; ++oc) {
        float bv = b1[oc];
        float4 res;
        res.x = (rowv && owb + 0 < 122) ? acc[oc][0] + bv : 0.f;
        res.y = (rowv && owb + 1 < 122) ? acc[oc][1] + bv : 0.f;
        res.z = (rowv && owb + 2 < 122) ? acc[oc][2] + bv : 0.f;
        res.w = (rowv && owb + 3 < 122) ? acc[oc][3] + bv : 0.f;
        *(float4*)&out[(((size_t)b * 4 + oc) << 14) + (oh << 7) + owb] = res;
    }
}

// ---------------- 7x7 conv, 4->4, pad 3, canonical weights [oc][ic][kh][kw], optional skip ----------------
__global__ __launch_bounds__(256) void conv7_kernel(
    const float* __restrict__ in, const float* __restrict__ w,
    const float* __restrict__ bias, const float* __restrict__ skip,
    float* __restrict__ out)
{
    __shared__ float tile[4][38][40];
    int tx = blockIdx.x, ty = blockIdx.y, b = blockIdx.z;
    int tid = threadIdx.x;
    int r0g = ty * 32 - 3, c0g = tx * 32 - 3;
    for (int i = tid; i < 4 * 38 * 38; i += 256) {
        int ic = i / 1444;
        int rem = i - ic * 1444;
        int rr = rem / 38, cc = rem - rr * 38;
        int gi = r0g + rr, gj = c0g + cc;
        float v = 0.f;
        if (gi >= 0 && gi < 128 && gj >= 0 && gj < 128)
            v = in[(((size_t)b * 4 + ic) << 14) + (gi << 7) + gj];
        tile[ic][rr][cc] = v;
    }
    __syncthreads();
    int cg = tid & 7, r = tid >> 3;
    int B = cg * 4;
    float acc[4][4];
#pragma unroll
    for (int oc = 0; oc < 4; ++oc)
#pragma unroll
        for (int c = 0; c < 4; ++c) acc[oc][c] = 0.f;
#pragma unroll 1
    for (int ic = 0; ic < 4; ++ic) {
#pragma unroll 1
        for (int kh = 0; kh < 7; ++kh) {
            float win[12];
            const float* trow = &tile[ic][r + kh][B];
#pragma unroll
            for (int k = 0; k < 3; ++k)
                *(float4*)&win[4 * k] = *(const float4*)&trow[4 * k];
#pragma unroll
            for (int oc = 0; oc < 4; ++oc) {
                const float* wr = w + (oc * 4 + ic) * 49 + kh * 7;
#pragma unroll
                for (int kw = 0; kw < 7; ++kw) {
                    float wv = wr[kw];
#pragma unroll
                    for (int c = 0; c < 4; ++c)
                        acc[oc][c] = fmaf(win[c + kw], wv, acc[oc][c]);
                }
            }
        }
    }
    int oh = ty * 32 + r;
    int owb = tx * 32 + B;
    bool rowv = oh < 122;
#pragma unroll
    for (int oc = 0; oc < 4; ++oc) {
        size_t o = (((size_t)b * 4 + oc) << 14) + (oh << 7) + owb;
        float4 sv = make_float4(0.f, 0.f, 0.f, 0.f);
        if (skip) sv = *(const float4*)&skip[o];
        float bv = bias[oc];
        float4 res;
        res.x = (rowv && owb + 0 < 122) ? acc[oc][0] + bv + sv.x : 0.f;
        res.y = (rowv && owb + 1 < 122) ? acc[oc][1] + bv + sv.y : 0.f;
        res.z = (rowv && owb + 2 < 122) ? acc[oc][2] + bv + sv.z : 0.f;
        res.w = (rowv && owb + 3 < 122) ? acc[oc][3] + bv + sv.w : 0.f;
        *(float4*)&out[o] = res;
    }
}

// ---------------- convT4: 4->1, k16, s2, p1, parity-decomposed; then * x ----------------
#define CT_HALF(T, ROW, PA)                                                    \
    _Pragma("unroll")                                                          \
    for (int pb = 0; pb < 2; ++pb) {                                           \
        const float* w8 = wp + (((ic * 2 + (PA)) * 2 + pb) * 8 + (T)) * 8;     \
        _Pragma("unroll")                                                      \
        for (int u = 0; u < 8; ++u) {                                          \
            float wv = w8[u];                                                  \
            _Pragma("unroll")                                                  \
            for (int c = 0; c < 4; ++c)                                        \
                acc[PA][pb][c] = fmaf(ROW[8 + c + pb - u], wv, acc[PA][pb][c]);\
        }                                                                      \
    }

__global__ __launch_bounds__(256) void convt4_kernel(
    const float* __restrict__ in, const float* __restrict__ wp,
    const float* __restrict__ bias, const float* __restrict__ xin,
    float* __restrict__ out)
{
    __shared__ float tile[4][40][44];
    int tx = blockIdx.x, ty = blockIdx.y, b = blockIdx.z;
    int tid = threadIdx.x;
    int A0 = ty * 32, B0 = tx * 32;
    int r0g = A0 - 7, c0g = B0 - 8;
    for (int i = tid; i < 4 * 40 * 44; i += 256) {
        int ic = i / 1760;
        int rem = i - ic * 1760;
        int rr = rem / 44, cc = rem - rr * 44;
        int gi = r0g + rr, gj = c0g + cc;
        float v = 0.f;
        if (gi >= 0 && gi < 128 && gj >= 0 && gj < 128)
            v = in[(((size_t)b * 4 + ic) << 14) + (gi << 7) + gj];
        tile[ic][rr][cc] = v;
    }
    __syncthreads();
    int cg = tid & 7, ra = tid >> 3;
    float acc[2][2][4];
#pragma unroll
    for (int pa = 0; pa < 2; ++pa)
#pragma unroll
        for (int pb = 0; pb < 2; ++pb)
#pragma unroll
            for (int c = 0; c < 4; ++c) acc[pa][pb][c] = 0.f;
#pragma unroll 1
    for (int ic = 0; ic < 4; ++ic) {
        float bufA[16], bufB[16];
#pragma unroll
        for (int k = 0; k < 4; ++k)
            *(float4*)&bufB[4 * k] = *(const float4*)&tile[ic][ra + 8][4 * cg + 4 * k];
#pragma unroll 1
        for (int t2 = 0; t2 < 8; t2 += 2) {
#pragma unroll
            for (int k = 0; k < 4; ++k)
                *(float4*)&bufA[4 * k] = *(const float4*)&tile[ic][ra + 7 - t2][4 * cg + 4 * k];
            CT_HALF(t2, bufA, 0)
            CT_HALF(t2, bufB, 1)
#pragma unroll
            for (int k = 0; k < 4; ++k)
                *(float4*)&bufB[4 * k] = *(const float4*)&tile[ic][ra + 6 - t2][4 * cg + 4 * k];
            CT_HALF(t2 + 1, bufB, 0)
            CT_HALF(t2 + 1, bufA, 1)
        }
    }
    int oh0 = 2 * (A0 + ra);
    int owb = 2 * (B0 + 4 * cg);
    float bv = bias[0];
#pragma unroll
    for (int pa = 0; pa < 2; ++pa) {
        size_t o = (size_t)b * 65536 + (size_t)(oh0 + pa) * 256 + owb;
        float4 x0 = *(const float4*)&xin[o];
        float4 x1 = *(const float4*)&xin[o + 4];
        float4 r0, r1;
        r0.x = (acc[pa][0][0] + bv) * x0.x;
        r0.y = (acc[pa][1][0] + bv) * x0.y;
        r0.z = (acc[pa][0][1] + bv) * x0.z;
        r0.w = (acc[pa][1][1] + bv) * x0.w;
        r1.x = (acc[pa][0][2] + bv) * x1.x;
        r1.y = (acc[pa][1][2] + bv) * x1.y;
        r1.z = (acc[pa][0][3] + bv) * x1.z;
        r1.w = (acc[pa][1][3] + bv) * x1.w;
        *(float4*)&out[o] = r0;
        *(float4*)&out[o + 4] = r1;
    }
}

// ---------------- TV loss (per-block partial, no atomics) ----------------
__global__ __launch_bounds__(256) void tv_kernel(
    const float* __restrict__ out, float* __restrict__ tvpart)
{
    __shared__ float red[256];
    int tid = threadIdx.x;
    float local = 0.f;
    const int total = 128 * 65536;
    for (int idx = blockIdx.x * 256 + tid; idx < total; idx += gridDim.x * 256) {
        float v = out[idx];
        int hw = idx & 65535;
        if (hw < 65280) local += fabsf(out[idx + 256] - v);
        if ((idx & 255) != 255) local += fabsf(out[idx + 1] - v);
    }
    red[tid] = local;
    __syncthreads();
    for (int s = 128; s > 0; s >>= 1) {
        if (tid < s) red[tid] += red[tid + s];
        __syncthreads();
    }
    if (tid == 0) tvpart[blockIdx.x] = red[0];
}

// ---------------- finalize: reduce KL partials + TV partials -> loss ----------------
__global__ __launch_bounds__(256) void finalize_kernel(
    const float* __restrict__ klpart,  // [3][2048][64]
    const float* __restrict__ tvpart,  // [2048]
    float* __restrict__ lossout)
{
    __shared__ float redm[3][256];
    __shared__ float tvred[256];
    int tid = threadIdx.x;
    int sub = tid >> 6, t = tid & 63;
    float s0 = 0.f, s1 = 0.f, s2 = 0.f;
    for (int r = sub; r < 2048; r += 4) {
        s0 += klpart[0 * 131072 + r * 64 + t];
        s1 += klpart[1 * 131072 + r * 64 + t];
        s2 += klpart[2 * 131072 + r * 64 + t];
    }
    redm[0][tid] = s0; redm[1][tid] = s1; redm[2][tid] = s2;
    float tvs = 0.f;
    for (int i = tid; i < 2048; i += 256) tvs += tvpart[i];
    tvred[tid] = tvs;
    __syncthreads();
    if (tid < 128) tvred[tid] += tvred[tid + 128];
    __syncthreads();
    if (tid < 64) {
        float tvv = tvred[t] + tvred[t + 64];
        float p = 1.f / (1.f + __expf(-0.001f));
        float term = 0.f;
#pragma unroll
        for (int l = 0; l < 3; ++l) {
            float q = redm[l][t] + redm[l][t + 64] + redm[l][t + 128] + redm[l][t + 192];
            float qm = q * (1.f / 131072.f);
            term += p * logf(p / qm) + (1.f - p) * logf((1.f - p) / (1.f - qm));
        }
#pragma unroll
        for (int off = 32; off > 0; off >>= 1) {
            term += __shfl_down(term, off);
            tvv  += __shfl_down(tvv, off);
        }
        if (t == 0)
            lossout[0] = 0.05f * tvv / 8388608.f + 0.1f * term;
    }
}

extern "C" void kernel_launch(void* const* d_in, const int* in_sizes, int n_in,
                              void* d_out, int out_size, void* d_ws, size_t ws_size,
                              hipStream_t stream) {
    (void)in_sizes; (void)n_in; (void)out_size; (void)ws_size;
    const float* x  = (const float*)d_in[0];
    const float* v1 = (const float*)d_in[2];
    const float* T1 = (const float*)d_in[3];
    const float* v2 = (const float*)d_in[4];
    const float* T2 = (const float*)d_in[5];
    const float* v3 = (const float*)d_in[6];
    const float* T3 = (const float*)d_in[7];
    const float* w1 = (const float*)d_in[8];
    const float* b1 = (const float*)d_in[9];
    const float* w2 = (const float*)d_in[10];
    const float* b2 = (const float*)d_in[11];
    const float* w3 = (const float*)d_in[12];
    const float* b3 = (const float*)d_in[13];
    const float* w4 = (const float*)d_in[14];
    const float* b4 = (const float*)d_in[15];
    float* out = (float*)d_out;

    float* W0 = (float*)d_ws;
    float* W1 = W0 + (size_t)NPLANES * PLANE;
    float* W2 = W1 + (size_t)NPLANES * PLANE;
    float* klpart = W2 + (size_t)NPLANES * PLANE; // [3][2048][64] = 393216 floats
    float* tvpart = klpart + 3 * 2048 * 64;        // [2048]
    float* w3c = tvpart + 2048;                     // 784 floats
    float* w4p = w3c + 784;                         // 1024 floats
    float* x10buf = out;                            // reuse d_out region as x10 scratch

    prep_weights<<<4, 256, 0, stream>>>(w3, w4, w3c, w4p);
    // x1 (padded) -> W0
    conv1_kernel<<<dim3(4, 4, 128), 256, 0, stream>>>(x, w1, b1, W0);
    // x6 -> W1, x9 -> W2, KL1 partials
    fwht_kernel_t<true, false><<<NPLANES, 256, 0, stream>>>(W0, v1, T1, nullptr, W1, W2, klpart);
    // x10 -> d_out scratch
    conv7_kernel<<<dim3(4, 4, 128), 256, 0, stream>>>(W2, w2, b2, nullptr, x10buf);
    // x15 (not stored), KL2 partials, x18 -> W0
    fwht_kernel_t<false, false><<<NPLANES, 256, 0, stream>>>(x10buf, v2, T2, nullptr, nullptr, W0, klpart + 131072);
    // x19 = convT3(x18) + x10 -> W2
    conv7_kernel<<<dim3(4, 4, 128), 256, 0, stream>>>(W0, w3c, b3, x10buf, W2);
    // x24 (not stored), KL3 partials, +x6, x27 -> W0
    fwht_kernel_t<false, true><<<NPLANES, 256, 0, stream>>>(W2, v3, T3, W1, nullptr, W0, klpart + 2 * 131072);
    // out = convT4(x27) * x
    convt4_kernel<<<dim3(4, 4, 128), 256, 0, stream>>>(W0, w4p, b4, x, out);
    // TV partials on out
    tv_kernel<<<2048, 256, 0, stream>>>(out, tvpart);
    // loss scalar
    finalize_kernel<<<1, 256, 0, stream>>>(klpart, tvpart, out + 8388608);
}

// Round 5
// 375.049 us; speedup vs baseline: 2.5164x; 1.3634x over previous
//
#include <hip/hip_runtime.h>
#include <math.h>

#define PLANE 16384   // 128*128
#define NPLANES 512   // B(128) * C(4)

// ---------------- in-register 2D FWHT-128x128 across a 256-thread block ----------------
// Thread (W = tid>>6, L = tid&63) holds v[g*4+c] = plane[h][w],
//   h = W*32 + (L>>5)*16 + g   (g in [0,16))
//   w = (L&31)*4 + c           (c in [0,4))
__device__ __forceinline__ void fwht2d_reg(float* __restrict__ v, float* __restrict__ xch,
                                           int W, int L) {
    // w bits 0-1: in-register
#pragma unroll
    for (int m = 1; m <= 2; m <<= 1) {
#pragma unroll
        for (int r = 0; r < 64; ++r) {
            if (!(r & m)) {
                int s = r | m;
                float a = v[r], b = v[s];
                v[r] = a + b; v[s] = a - b;
            }
        }
    }
    // w bits 2-6 and h bit 4: cross-lane shuffle stages
#pragma unroll
    for (int m = 1; m <= 32; m <<= 1) {
        float sg = (L & m) ? -1.f : 1.f;
#pragma unroll
        for (int r = 0; r < 64; ++r) {
            float p = __shfl_xor(v[r], m);
            v[r] = fmaf(sg, v[r], p);
        }
    }
    // h bits 0-3: in-register
#pragma unroll
    for (int m = 4; m <= 32; m <<= 1) {
#pragma unroll
        for (int r = 0; r < 64; ++r) {
            if (!(r & m)) {
                int s = r | m;
                float a = v[r], b = v[s];
                v[r] = a + b; v[s] = a - b;
            }
        }
    }
    // h bits 5-6 (wave index): LDS exchange, 2 stages x 2 reg-chunks, conflict-free layout
#pragma unroll
    for (int mw = 1; mw <= 2; mw <<= 1) {
        int Wp = W ^ mw;
        float sg = (W & mw) ? -1.f : 1.f;
#pragma unroll
        for (int half = 0; half < 2; ++half) {
            __syncthreads();
#pragma unroll
            for (int j = 0; j < 32; ++j)
                xch[(j * 4 + W) * 64 + L] = v[half * 32 + j];
            __syncthreads();
#pragma unroll
            for (int j = 0; j < 32; ++j) {
                float p = xch[(j * 4 + Wp) * 64 + L];
                v[half * 32 + j] = fmaf(sg, v[half * 32 + j], p);
            }
        }
    }
}

template <bool STORET, bool ADD>
__global__ __launch_bounds__(256) void fwht_kernel_t(
    const float* __restrict__ in, const float* __restrict__ vmat,
    const float* __restrict__ tmat, const float* __restrict__ addbuf,
    float* __restrict__ outThresh, float* __restrict__ outInv,
    float* __restrict__ klpart)   // per-wave partial rows [NPLANES*4][64]
{
    __shared__ float xch[32 * 256]; // 32 KiB
    const int tid = threadIdx.x;
    const int W = tid >> 6, L = tid & 63;
    const int plane = blockIdx.x;
    const int hbase = W * 32 + ((L >> 5) << 4);
    const int wbase = (L & 31) << 2;
    const float* src = in + (size_t)plane * PLANE;

    float v[64];
#pragma unroll
    for (int g = 0; g < 16; ++g) {
        float4 t = *(const float4*)&src[(hbase + g) * 128 + wbase];
        v[4 * g] = t.x; v[4 * g + 1] = t.y; v[4 * g + 2] = t.z; v[4 * g + 3] = t.w;
    }

    fwht2d_reg(v, xch, W, L);

    // pointwise: *vmat, hard-threshold, KL accumulate, optional store / add
    float ls0 = 0.f, ls1 = 0.f, ls2 = 0.f, ls3 = 0.f;
#pragma unroll
    for (int g = 0; g < 16; ++g) {
        int rowoff = (hbase + g) * 128 + wbase;
        float4 vm = *(const float4*)&vmat[rowoff];
        float4 tm = *(const float4*)&tmat[rowoff];
        float y0 = v[4 * g]     * vm.x;
        float y1 = v[4 * g + 1] * vm.y;
        float y2 = v[4 * g + 2] * vm.z;
        float y3 = v[4 * g + 3] * vm.w;
        y0 = (fabsf(y0) > fabsf(tm.x)) ? y0 : 0.f;
        y1 = (fabsf(y1) > fabsf(tm.y)) ? y1 : 0.f;
        y2 = (fabsf(y2) > fabsf(tm.z)) ? y2 : 0.f;
        y3 = (fabsf(y3) > fabsf(tm.w)) ? y3 : 0.f;
        ls0 += 1.f / (1.f + __expf(-fabsf(y0)));
        ls1 += 1.f / (1.f + __expf(-fabsf(y1)));
        ls2 += 1.f / (1.f + __expf(-fabsf(y2)));
        ls3 += 1.f / (1.f + __expf(-fabsf(y3)));
        if (STORET) {
            float4 o; o.x = y0; o.y = y1; o.z = y2; o.w = y3;
            *(float4*)&outThresh[(size_t)plane * PLANE + rowoff] = o;
        }
        if (ADD) {
            float4 ad = *(const float4*)&addbuf[(size_t)plane * PLANE + rowoff];
            y0 += ad.x; y1 += ad.y; y2 += ad.z; y3 += ad.w;
        }
        v[4 * g] = y0; v[4 * g + 1] = y1; v[4 * g + 2] = y2; v[4 * g + 3] = y3;
    }
    // KL bins: bin = w%64 = (L&15)*4 + c. Reduce lanes sharing (L&15), then one
    // coalesced float4 store per wave into a private partial row (NO atomics).
#pragma unroll
    for (int m = 16; m <= 32; m <<= 1) {
        ls0 += __shfl_xor(ls0, m);
        ls1 += __shfl_xor(ls1, m);
        ls2 += __shfl_xor(ls2, m);
        ls3 += __shfl_xor(ls3, m);
    }
    if (L < 16) {
        float4 o; o.x = ls0; o.y = ls1; o.z = ls2; o.w = ls3;
        *(float4*)&klpart[(size_t)(plane * 4 + W) * 64 + 4 * L] = o;
    }

    fwht2d_reg(v, xch, W, L);

    // scale 1/16384, crop to 122x122 (zero pad), store
    float* dst = outInv + (size_t)plane * PLANE;
    const float s = 1.f / 16384.f;
#pragma unroll
    for (int g = 0; g < 16; ++g) {
        int h = hbase + g;
        bool rv = h < 122;
        float4 o;
        o.x = (rv && wbase + 0 < 122) ? v[4 * g]     * s : 0.f;
        o.y = (rv && wbase + 1 < 122) ? v[4 * g + 1] * s : 0.f;
        o.z = (rv && wbase + 2 < 122) ? v[4 * g + 2] * s : 0.f;
        o.w = (rv && wbase + 3 < 122) ? v[4 * g + 3] * s : 0.f;
        *(float4*)&dst[h * 128 + wbase] = o;
    }
}

// ---------------- weight prep: canonicalize w3 (transposed 7x7) and w4 (convT 16x16 s2) ----------------
__global__ void prep_weights(const float* __restrict__ w3, const float* __restrict__ w4,
                             float* __restrict__ w3c, float* __restrict__ w4p)
{
    int tid = blockIdx.x * 256 + threadIdx.x;
    if (tid < 784) {
        int oc = tid / 196;
        int rem = tid - oc * 196;
        int ic = rem / 49;
        int k = rem - ic * 49;
        int kh = k / 7, kw = k - kh * 7;
        w3c[(oc * 4 + ic) * 49 + k] = w3[(ic * 4 + oc) * 49 + (6 - kh) * 7 + (6 - kw)];
    }
    if (tid < 1024) {
        // layout [ic:2][pa:1][pb:1][t:3][u:3]
        int u = tid & 7, t = (tid >> 3) & 7, pb = (tid >> 6) & 1, pa = (tid >> 7) & 1, ic = tid >> 8;
        int kh = 2 * t + (pa ? 0 : 1);
        int kw = 2 * u + (pb ? 0 : 1);
        w4p[tid] = w4[ic * 256 + kh * 16 + kw];
    }
}

// ---------------- conv1: 1->4, k16, s2, p1 : x[B,1,256,256] -> [B,4,128,128] padded ----------------
__global__ __launch_bounds__(256) void conv1_kernel(
    const float* __restrict__ x, const float* __restrict__ w1,
    const float* __restrict__ b1, float* __restrict__ out)
{
    __shared__ float tile[78][80];
    int tx = blockIdx.x, ty = blockIdx.y, b = blockIdx.z;
    int tid = threadIdx.x;
    const float* xp = x + (size_t)b * 65536;
    int r0g = ty * 64 - 1, c0g = tx * 64 - 1;
    for (int i = tid; i < 78 * 78; i += 256) {
        int rr = i / 78, cc = i - rr * 78;
        int gi = r0g + rr, gj = c0g + cc;
        tile[rr][cc] = (gi >= 0 && gi < 256 && gj >= 0 && gj < 256) ? xp[gi * 256 + gj] : 0.f;
    }
    __syncthreads();
    int cg = tid & 7, r = tid >> 3;
    int B = cg * 4;
    float acc[4][4];
#pragma unroll
    for (int oc = 0; oc < 4; ++oc)
#pragma unroll
        for (int c = 0; c < 4; ++c) acc[oc][c] = 0.f;
#pragma unroll 1
    for (int kh = 0; kh < 16; ++kh) {
        float win[24];
        const float* trow = &tile[2 * r + kh][2 * B];
#pragma unroll
        for (int k = 0; k < 6; ++k)
            *(float4*)&win[4 * k] = *(const float4*)&trow[4 * k];
#pragma unroll
        for (int oc = 0; oc < 4; ++oc) {
            const float* wr = w1 + oc * 256 + kh * 16;
#pragma unroll
            for (int kw = 0; kw < 16; ++kw) {
                float wv = wr[kw];
#pragma unroll
                for (int c = 0; c < 4; ++c)
                    acc[oc][c] = fmaf(win[2 * c + kw], wv, acc[oc][c]);
            }
        }
    }
    int oh = ty * 32 + r;
    int owb = tx * 32 + B;
    bool rowv = oh < 122;
#pragma unroll
    for (int oc = 0; oc < 4; ++oc) {
        float bv = b1[oc];
        float4 res;
        res.x = (rowv && owb + 0 < 122) ? acc[oc][0] + bv : 0.f;
        res.y = (rowv && owb + 1 < 122) ? acc[oc][1] + bv : 0.f;
        res.z = (rowv && owb + 2 < 122) ? acc[oc][2] + bv : 0.f;
        res.w = (rowv && owb + 3 < 122) ? acc[oc][3] + bv : 0.f;
        *(float4*)&out[(((size_t)b * 4 + oc) << 14) + (oh << 7) + owb] = res;
    }
}

// ---------------- 7x7 conv, 4->4, pad 3, canonical weights [oc][ic][kh][kw], optional skip ----------------
__global__ __launch_bounds__(256) void conv7_kernel(
    const float* __restrict__ in, const float* __restrict__ w,
    const float* __restrict__ bias, const float* __restrict__ skip,
    float* __restrict__ out)
{
    __shared__ float tile[4][38][40];
    int tx = blockIdx.x, ty = blockIdx.y, b = blockIdx.z;
    int tid = threadIdx.x;
    int r0g = ty * 32 - 3, c0g = tx * 32 - 3;
    for (int i = tid; i < 4 * 38 * 38; i += 256) {
        int ic = i / 1444;
        int rem = i - ic * 1444;
        int rr = rem / 38, cc = rem - rr * 38;
        int gi = r0g + rr, gj = c0g + cc;
        float v = 0.f;
        if (gi >= 0 && gi < 128 && gj >= 0 && gj < 128)
            v = in[(((size_t)b * 4 + ic) << 14) + (gi << 7) + gj];
        tile[ic][rr][cc] = v;
    }
    __syncthreads();
    int cg = tid & 7, r = tid >> 3;
    int B = cg * 4;
    float acc[4][4];
#pragma unroll
    for (int oc = 0; oc < 4; ++oc)
#pragma unroll
        for (int c = 0; c < 4; ++c) acc[oc][c] = 0.f;
#pragma unroll 1
    for (int ic = 0; ic < 4; ++ic) {
#pragma unroll 1
        for (int kh = 0; kh < 7; ++kh) {
            float win[12];
            const float* trow = &tile[ic][r + kh][B];
#pragma unroll
            for (int k = 0; k < 3; ++k)
                *(float4*)&win[4 * k] = *(const float4*)&trow[4 * k];
#pragma unroll
            for (int oc = 0; oc < 4; ++oc) {
                const float* wr = w + (oc * 4 + ic) * 49 + kh * 7;
#pragma unroll
                for (int kw = 0; kw < 7; ++kw) {
                    float wv = wr[kw];
#pragma unroll
                    for (int c = 0; c < 4; ++c)
                        acc[oc][c] = fmaf(win[c + kw], wv, acc[oc][c]);
                }
            }
        }
    }
    int oh = ty * 32 + r;
    int owb = tx * 32 + B;
    bool rowv = oh < 122;
#pragma unroll
    for (int oc = 0; oc < 4; ++oc) {
        size_t o = (((size_t)b * 4 + oc) << 14) + (oh << 7) + owb;
        float4 sv = make_float4(0.f, 0.f, 0.f, 0.f);
        if (skip) sv = *(const float4*)&skip[o];
        float bv = bias[oc];
        float4 res;
        res.x = (rowv && owb + 0 < 122) ? acc[oc][0] + bv + sv.x : 0.f;
        res.y = (rowv && owb + 1 < 122) ? acc[oc][1] + bv + sv.y : 0.f;
        res.z = (rowv && owb + 2 < 122) ? acc[oc][2] + bv + sv.z : 0.f;
        res.w = (rowv && owb + 3 < 122) ? acc[oc][3] + bv + sv.w : 0.f;
        *(float4*)&out[o] = res;
    }
}

// ---------------- convT4: 4->1, k16, s2, p1, parity-decomposed; then * x ----------------
#define CT_HALF(T, ROW, PA)                                                    \
    _Pragma("unroll")                                                          \
    for (int pb = 0; pb < 2; ++pb) {                                           \
        const float* w8 = wp + (((ic * 2 + (PA)) * 2 + pb) * 8 + (T)) * 8;     \
        _Pragma("unroll")                                                      \
        for (int u = 0; u < 8; ++u) {                                          \
            float wv = w8[u];                                                  \
            _Pragma("unroll")                                                  \
            for (int c = 0; c < 4; ++c)                                        \
                acc[PA][pb][c] = fmaf(ROW[8 + c + pb - u], wv, acc[PA][pb][c]);\
        }                                                                      \
    }

__global__ __launch_bounds__(256) void convt4_kernel(
    const float* __restrict__ in, const float* __restrict__ wp,
    const float* __restrict__ bias, const float* __restrict__ xin,
    float* __restrict__ out)
{
    __shared__ float tile[4][40][44];
    int tx = blockIdx.x, ty = blockIdx.y, b = blockIdx.z;
    int tid = threadIdx.x;
    int A0 = ty * 32, B0 = tx * 32;
    int r0g = A0 - 7, c0g = B0 - 8;
    for (int i = tid; i < 4 * 40 * 44; i += 256) {
        int ic = i / 1760;
        int rem = i - ic * 1760;
        int rr = rem / 44, cc = rem - rr * 44;
        int gi = r0g + rr, gj = c0g + cc;
        float v = 0.f;
        if (gi >= 0 && gi < 128 && gj >= 0 && gj < 128)
            v = in[(((size_t)b * 4 + ic) << 14) + (gi << 7) + gj];
        tile[ic][rr][cc] = v;
    }
    __syncthreads();
    int cg = tid & 7, ra = tid >> 3;
    float acc[2][2][4];
#pragma unroll
    for (int pa = 0; pa < 2; ++pa)
#pragma unroll
        for (int pb = 0; pb < 2; ++pb)
#pragma unroll
            for (int c = 0; c < 4; ++c) acc[pa][pb][c] = 0.f;
#pragma unroll 1
    for (int ic = 0; ic < 4; ++ic) {
        float bufA[16], bufB[16];
#pragma unroll
        for (int k = 0; k < 4; ++k)
            *(float4*)&bufB[4 * k] = *(const float4*)&tile[ic][ra + 8][4 * cg + 4 * k];
#pragma unroll 1
        for (int t2 = 0; t2 < 8; t2 += 2) {
#pragma unroll
            for (int k = 0; k < 4; ++k)
                *(float4*)&bufA[4 * k] = *(const float4*)&tile[ic][ra + 7 - t2][4 * cg + 4 * k];
            CT_HALF(t2, bufA, 0)
            CT_HALF(t2, bufB, 1)
#pragma unroll
            for (int k = 0; k < 4; ++k)
                *(float4*)&bufB[4 * k] = *(const float4*)&tile[ic][ra + 6 - t2][4 * cg + 4 * k];
            CT_HALF(t2 + 1, bufB, 0)
            CT_HALF(t2 + 1, bufA, 1)
        }
    }
    int oh0 = 2 * (A0 + ra);
    int owb = 2 * (B0 + 4 * cg);
    float bv = bias[0];
#pragma unroll
    for (int pa = 0; pa < 2; ++pa) {
        size_t o = (size_t)b * 65536 + (size_t)(oh0 + pa) * 256 + owb;
        float4 x0 = *(const float4*)&xin[o];
        float4 x1 = *(const float4*)&xin[o + 4];
        float4 r0, r1;
        r0.x = (acc[pa][0][0] + bv) * x0.x;
        r0.y = (acc[pa][1][0] + bv) * x0.y;
        r0.z = (acc[pa][0][1] + bv) * x0.z;
        r0.w = (acc[pa][1][1] + bv) * x0.w;
        r1.x = (acc[pa][0][2] + bv) * x1.x;
        r1.y = (acc[pa][1][2] + bv) * x1.y;
        r1.z = (acc[pa][0][3] + bv) * x1.z;
        r1.w = (acc[pa][1][3] + bv) * x1.w;
        *(float4*)&out[o] = r0;
        *(float4*)&out[o + 4] = r1;
    }
}

// ---------------- TV loss (per-block partial, no atomics) ----------------
__global__ __launch_bounds__(256) void tv_kernel(
    const float* __restrict__ out, float* __restrict__ tvpart)
{
    __shared__ float red[256];
    int tid = threadIdx.x;
    float local = 0.f;
    const int total = 128 * 65536;
    for (int idx = blockIdx.x * 256 + tid; idx < total; idx += gridDim.x * 256) {
        float v = out[idx];
        int hw = idx & 65535;
        if (hw < 65280) local += fabsf(out[idx + 256] - v);
        if ((idx & 255) != 255) local += fabsf(out[idx + 1] - v);
    }
    red[tid] = local;
    __syncthreads();
    for (int s = 128; s > 0; s >>= 1) {
        if (tid < s) red[tid] += red[tid + s];
        __syncthreads();
    }
    if (tid == 0) tvpart[blockIdx.x] = red[0];
}

// ---------------- stage-1 reduce: KL partials [3][2048][64] -> [3][16][64]; TV [2048] -> [1] ----------------
__global__ __launch_bounds__(256) void reduce1_kernel(
    const float* __restrict__ klpart, const float* __restrict__ tvpart,
    float* __restrict__ klred, float* __restrict__ tvred)
{
    int bid = blockIdx.x;
    int tid = threadIdx.x;
    if (bid < 48) {
        int layer = bid >> 4, chunk = bid & 15;
        int sub = tid >> 6, t = tid & 63;
        const float* base = klpart + (size_t)layer * 131072 + (size_t)chunk * 128 * 64;
        float s = 0.f;
        for (int r = sub; r < 128; r += 4)
            s += base[r * 64 + t];
        __shared__ float red[4][64];
        red[sub][t] = s;
        __syncthreads();
        if (tid < 64)
            klred[(layer * 16 + chunk) * 64 + tid] =
                red[0][tid] + red[1][tid] + red[2][tid] + red[3][tid];
    } else {
        __shared__ float red[256];
        float s = 0.f;
        for (int i = tid; i < 2048; i += 256) s += tvpart[i];
        red[tid] = s;
        __syncthreads();
        for (int st = 128; st > 0; st >>= 1) {
            if (tid < st) red[tid] += red[tid + st];
            __syncthreads();
        }
        if (tid == 0) tvred[0] = red[0];
    }
}

// ---------------- stage-2 finalize: [3][16][64] + tv -> loss ----------------
__global__ __launch_bounds__(64) void finalize2_kernel(
    const float* __restrict__ klred, const float* __restrict__ tvred,
    float* __restrict__ lossout)
{
    int t = threadIdx.x;
    float p = 1.f / (1.f + __expf(-0.001f));
    float term = 0.f;
#pragma unroll
    for (int l = 0; l < 3; ++l) {
        float q = 0.f;
#pragma unroll
        for (int c = 0; c < 16; ++c)
            q += klred[(l * 16 + c) * 64 + t];
        float qm = q * (1.f / 131072.f);
        term += p * logf(p / qm) + (1.f - p) * logf((1.f - p) / (1.f - qm));
    }
#pragma unroll
    for (int off = 32; off > 0; off >>= 1)
        term += __shfl_down(term, off);
    if (t == 0)
        lossout[0] = 0.05f * tvred[0] / 8388608.f + 0.1f * term;
}

extern "C" void kernel_launch(void* const* d_in, const int* in_sizes, int n_in,
                              void* d_out, int out_size, void* d_ws, size_t ws_size,
                              hipStream_t stream) {
    (void)in_sizes; (void)n_in; (void)out_size; (void)ws_size;
    const float* x  = (const float*)d_in[0];
    const float* v1 = (const float*)d_in[2];
    const float* T1 = (const float*)d_in[3];
    const float* v2 = (const float*)d_in[4];
    const float* T2 = (const float*)d_in[5];
    const float* v3 = (const float*)d_in[6];
    const float* T3 = (const float*)d_in[7];
    const float* w1 = (const float*)d_in[8];
    const float* b1 = (const float*)d_in[9];
    const float* w2 = (const float*)d_in[10];
    const float* b2 = (const float*)d_in[11];
    const float* w3 = (const float*)d_in[12];
    const float* b3 = (const float*)d_in[13];
    const float* w4 = (const float*)d_in[14];
    const float* b4 = (const float*)d_in[15];
    float* out = (float*)d_out;

    float* W0 = (float*)d_ws;
    float* W1 = W0 + (size_t)NPLANES * PLANE;
    float* W2 = W1 + (size_t)NPLANES * PLANE;
    float* klpart = W2 + (size_t)NPLANES * PLANE; // [3][2048][64] = 393216 floats
    float* tvpart = klpart + 3 * 2048 * 64;        // [2048]
    float* klred  = tvpart + 2048;                  // [3][16][64] = 3072
    float* tvred  = klred + 3072;                   // [1]
    float* w3c = tvred + 64;                        // 784 floats
    float* w4p = w3c + 784;                         // 1024 floats
    float* x10buf = out;                            // reuse d_out region as x10 scratch

    prep_weights<<<4, 256, 0, stream>>>(w3, w4, w3c, w4p);
    // x1 (padded) -> W0
    conv1_kernel<<<dim3(4, 4, 128), 256, 0, stream>>>(x, w1, b1, W0);
    // x6 -> W1, x9 -> W2, KL1 partials
    fwht_kernel_t<true, false><<<NPLANES, 256, 0, stream>>>(W0, v1, T1, nullptr, W1, W2, klpart);
    // x10 -> d_out scratch
    conv7_kernel<<<dim3(4, 4, 128), 256, 0, stream>>>(W2, w2, b2, nullptr, x10buf);
    // x15 (not stored), KL2 partials, x18 -> W0
    fwht_kernel_t<false, false><<<NPLANES, 256, 0, stream>>>(x10buf, v2, T2, nullptr, nullptr, W0, klpart + 131072);
    // x19 = convT3(x18) + x10 -> W2
    conv7_kernel<<<dim3(4, 4, 128), 256, 0, stream>>>(W0, w3c, b3, x10buf, W2);
    // x24 (not stored), KL3 partials, +x6, x27 -> W0
    fwht_kernel_t<false, true><<<NPLANES, 256, 0, stream>>>(W2, v3, T3, W1, nullptr, W0, klpart + 2 * 131072);
    // out = convT4(x27) * x
    convt4_kernel<<<dim3(4, 4, 128), 256, 0, stream>>>(W0, w4p, b4, x, out);
    // TV partials on out
    tv_kernel<<<2048, 256, 0, stream>>>(out, tvpart);
    // stage-1 reduce + finalize
    reduce1_kernel<<<49, 256, 0, stream>>>(klpart, tvpart, klred, tvred);
    finalize2_kernel<<<1, 64, 0, stream>>>(klred, tvred, out + 8388608);
}